// Round 2
// baseline (579.870 us; speedup 1.0000x reference)
//
#include <hip/hip_runtime.h>
#include <math.h>

#define NN 50000
#define EE 800000
#define D128 128
#define LN_EPSF 1e-5f

typedef __bf16 bf16_t;
typedef __bf16 bf16x8 __attribute__((ext_vector_type(8)));
typedef float f32x4 __attribute__((ext_vector_type(4)));

// ws float layout: [0 .. NN*D128) agg ; then scalars: [s1, s2, flag(int), ...pad to 64]
#define AGG_F (NN * D128)

__device__ __forceinline__ bf16x8 cvt8(float4 f0, float4 f1) {
    bf16x8 r;
    r[0] = (bf16_t)f0.x; r[1] = (bf16_t)f0.y; r[2] = (bf16_t)f0.z; r[3] = (bf16_t)f0.w;
    r[4] = (bf16_t)f1.x; r[5] = (bf16_t)f1.y; r[6] = (bf16_t)f1.z; r[7] = (bf16_t)f1.w;
    return r;
}

__device__ __forceinline__ bf16x8 zero8() {
    bf16x8 z;
    #pragma unroll
    for (int j = 0; j < 8; ++j) z[j] = (bf16_t)0.f;
    return z;
}

// Load W (fp32 [k][n]) into LDS as bf16 transposed [n][k], XOR-swizzled so that
// B-fragment ds_read_b128 (8 consecutive k per lane) is ~conflict-free.
__device__ __forceinline__ void load_w_lds(const float* __restrict__ W, bf16_t* Wlds,
                                           const float* __restrict__ bias, float* b_s) {
    int tid = threadIdx.x;
    for (int i = tid; i < D128 * D128; i += 256) {
        int k = i >> 7, n = i & 127;
        Wlds[(n * D128 + k) ^ ((n & 7) << 3)] = (bf16_t)W[i];
    }
    if (tid < D128) b_s[tid] = bias[tid];
    __syncthreads();
}

// detect whether edge_index is int64 (all high dwords of first 64 entries == 0)
__global__ void k_detect(const int* __restrict__ ei32, int* __restrict__ flag) {
    int i = threadIdx.x;
    unsigned long long m = __ballot(ei32[2 * i + 1] == 0);
    if (i == 0) flag[0] = (m == ~0ULL) ? 1 : 0;
}

__device__ __forceinline__ void idx_pair(const void* ei, int is64, int e, int& sj, int& di) {
    if (is64) {
        const long long* p = (const long long*)ei;
        sj = (int)p[e]; di = (int)p[EE + e];
    } else {
        const int* p = (const int*)ei;
        sj = p[e]; di = p[EE + e];
    }
}

// e = edge_attr @ Wl + bl ; msg = relu(x[src] + e) ; agg[dst] += msg (atomics)
__global__ __launch_bounds__(256) void k_edge(
    const float* __restrict__ ea, const void* __restrict__ eidx,
    const float* __restrict__ x, const float* __restrict__ Wl,
    const float* __restrict__ bl, float* __restrict__ agg,
    const int* __restrict__ flag)
{
    __shared__ bf16_t Wlds[D128 * D128];
    __shared__ float bl_s[D128];
    load_w_lds(Wl, Wlds, bl, bl_s);

    const int is64 = flag[0];
    const int lane = threadIdx.x & 63, wid = threadIdx.x >> 6;
    const int l15 = lane & 15, lg = lane >> 4;
    const int ntiles = EE / 64;  // 12500 exact, no tail

    for (int tile = blockIdx.x; tile < ntiles; tile += gridDim.x) {
        const int ebase = tile * 64 + wid * 16;
        // A fragments: 16 edges x K=128 (4 k-steps)
        bf16x8 a[4];
        {
            const float* rp = ea + (size_t)(ebase + l15) * D128 + lg * 8;
            #pragma unroll
            for (int s = 0; s < 4; ++s) {
                float4 f0 = *(const float4*)(rp + s * 32);
                float4 f1 = *(const float4*)(rp + s * 32 + 4);
                a[s] = cvt8(f0, f1);
            }
        }
        f32x4 acc[8];
        #pragma unroll
        for (int t = 0; t < 8; ++t) acc[t] = f32x4{0.f, 0.f, 0.f, 0.f};
        #pragma unroll
        for (int s = 0; s < 4; ++s) {
            const int kb = s * 32 + lg * 8;
            #pragma unroll
            for (int t = 0; t < 8; ++t) {
                const int col = l15 + 16 * t;
                bf16x8 b = *(const bf16x8*)&Wlds[(col * D128 + kb) ^ ((col & 7) << 3)];
                acc[t] = __builtin_amdgcn_mfma_f32_16x16x32_bf16(a[s], b, acc[t], 0, 0, 0);
            }
        }
        #pragma unroll
        for (int i = 0; i < 4; ++i) {
            const int e = ebase + lg * 4 + i;
            int sj, di;
            idx_pair(eidx, is64, e, sj, di);
            const float* xr = x + (size_t)sj * D128;
            float* ar = agg + (size_t)di * D128;
            #pragma unroll
            for (int t = 0; t < 8; ++t) {
                const int c = l15 + 16 * t;
                float v = fmaxf(acc[t][i] + bl_s[c] + xr[c], 0.0f);
                unsafeAtomicAdd(&ar[c], v);
            }
        }
    }
}

// t = relu((x+agg) @ W1 + b1)  -> stored fp32 into d_out (scratch use)
__global__ __launch_bounds__(256) void k_mlp1(
    const float* __restrict__ x, const float* __restrict__ agg,
    const float* __restrict__ W1, const float* __restrict__ b1,
    float* __restrict__ tbuf)
{
    __shared__ bf16_t Wlds[D128 * D128];
    __shared__ float b_s[D128];
    load_w_lds(W1, Wlds, b1, b_s);

    const int lane = threadIdx.x & 63, wid = threadIdx.x >> 6;
    const int l15 = lane & 15, lg = lane >> 4;
    const int nbase = blockIdx.x * 64 + wid * 16;
    if (nbase >= NN) return;

    const int row = nbase + l15;
    bf16x8 a[4];
    if (row < NN) {
        const float* xr = x + (size_t)row * D128 + lg * 8;
        const float* gr = agg + (size_t)row * D128 + lg * 8;
        #pragma unroll
        for (int s = 0; s < 4; ++s) {
            float4 f0 = *(const float4*)(xr + s * 32);
            float4 f1 = *(const float4*)(xr + s * 32 + 4);
            float4 g0 = *(const float4*)(gr + s * 32);
            float4 g1 = *(const float4*)(gr + s * 32 + 4);
            float4 h0 = {f0.x + g0.x, f0.y + g0.y, f0.z + g0.z, f0.w + g0.w};
            float4 h1 = {f1.x + g1.x, f1.y + g1.y, f1.z + g1.z, f1.w + g1.w};
            a[s] = cvt8(h0, h1);
        }
    } else {
        #pragma unroll
        for (int s = 0; s < 4; ++s) a[s] = zero8();
    }
    f32x4 acc[8];
    #pragma unroll
    for (int t = 0; t < 8; ++t) acc[t] = f32x4{0.f, 0.f, 0.f, 0.f};
    #pragma unroll
    for (int s = 0; s < 4; ++s) {
        const int kb = s * 32 + lg * 8;
        #pragma unroll
        for (int t = 0; t < 8; ++t) {
            const int col = l15 + 16 * t;
            bf16x8 b = *(const bf16x8*)&Wlds[(col * D128 + kb) ^ ((col & 7) << 3)];
            acc[t] = __builtin_amdgcn_mfma_f32_16x16x32_bf16(a[s], b, acc[t], 0, 0, 0);
        }
    }
    #pragma unroll
    for (int i = 0; i < 4; ++i) {
        const int r = nbase + lg * 4 + i;
        if (r < NN) {
            float* tr = tbuf + (size_t)r * D128;
            #pragma unroll
            for (int t = 0; t < 8; ++t) {
                const int c = l15 + 16 * t;
                tr[c] = fmaxf(acc[t][i] + b_s[c], 0.0f);
            }
        }
    }
}

// h2 = t @ W2 + b2 + x  -> d_out (in place over t, row-safe) ; block partial sums -> sc
__global__ __launch_bounds__(256) void k_mlp2(
    const float* __restrict__ tbuf, const float* __restrict__ x,
    const float* __restrict__ W2, const float* __restrict__ b2,
    float* __restrict__ out, float* __restrict__ sc)
{
    __shared__ bf16_t Wlds[D128 * D128];
    __shared__ float b_s[D128];
    __shared__ float red[8];
    load_w_lds(W2, Wlds, b2, b_s);

    const int tid = threadIdx.x;
    const int lane = tid & 63, wid = tid >> 6;
    const int l15 = lane & 15, lg = lane >> 4;
    const int nbase = blockIdx.x * 64 + wid * 16;
    float s1 = 0.f, s2 = 0.f;

    if (nbase < NN) {
        const int row = nbase + l15;
        bf16x8 a[4];
        if (row < NN) {
            const float* rp = tbuf + (size_t)row * D128 + lg * 8;
            #pragma unroll
            for (int s = 0; s < 4; ++s) {
                float4 f0 = *(const float4*)(rp + s * 32);
                float4 f1 = *(const float4*)(rp + s * 32 + 4);
                a[s] = cvt8(f0, f1);
            }
        } else {
            #pragma unroll
            for (int s = 0; s < 4; ++s) a[s] = zero8();
        }
        f32x4 acc[8];
        #pragma unroll
        for (int t = 0; t < 8; ++t) acc[t] = f32x4{0.f, 0.f, 0.f, 0.f};
        #pragma unroll
        for (int s = 0; s < 4; ++s) {
            const int kb = s * 32 + lg * 8;
            #pragma unroll
            for (int t = 0; t < 8; ++t) {
                const int col = l15 + 16 * t;
                bf16x8 b = *(const bf16x8*)&Wlds[(col * D128 + kb) ^ ((col & 7) << 3)];
                acc[t] = __builtin_amdgcn_mfma_f32_16x16x32_bf16(a[s], b, acc[t], 0, 0, 0);
            }
        }
        #pragma unroll
        for (int i = 0; i < 4; ++i) {
            const int r = nbase + lg * 4 + i;
            if (r < NN) {
                #pragma unroll
                for (int t = 0; t < 8; ++t) {
                    const int c = l15 + 16 * t;
                    float v = acc[t][i] + b_s[c] + x[(size_t)r * D128 + c];
                    out[(size_t)r * D128 + c] = v;
                    s1 += v;
                    s2 += v * v;
                }
            }
        }
    }
    // block reduction (all threads participate)
    #pragma unroll
    for (int o = 32; o > 0; o >>= 1) {
        s1 += __shfl_xor(s1, o);
        s2 += __shfl_xor(s2, o);
    }
    if (lane == 0) { red[wid * 2] = s1; red[wid * 2 + 1] = s2; }
    __syncthreads();
    if (tid == 0) {
        float a1 = red[0] + red[2] + red[4] + red[6];
        float a2 = red[1] + red[3] + red[5] + red[7];
        unsafeAtomicAdd(&sc[0], a1);
        unsafeAtomicAdd(&sc[1], a2);
    }
}

// graph-LN + SiLU + nan_to_num, in place on d_out
__global__ __launch_bounds__(256) void k_ln(
    float* __restrict__ out, const float* __restrict__ sc,
    const float* __restrict__ lnw, const float* __restrict__ lnb)
{
    const float inv = 1.0f / (float)(NN * D128);
    const float mu = sc[0] * inv;
    const float var = sc[1] * inv - mu * mu;
    const float rstd = 1.0f / (sqrtf(fmaxf(var, 0.f)) + LN_EPSF);
    const int total = NN * D128 / 4;
    for (int idx = blockIdx.x * 256 + threadIdx.x; idx < total; idx += gridDim.x * 256) {
        float4 h = ((const float4*)out)[idx];
        const int c0 = (idx * 4) & 127;
        float4 w = *(const float4*)(lnw + c0);
        float4 bb = *(const float4*)(lnb + c0);
        float4 r;
        r.x = (h.x - mu) * rstd * w.x + bb.x;
        r.y = (h.y - mu) * rstd * w.y + bb.y;
        r.z = (h.z - mu) * rstd * w.z + bb.z;
        r.w = (h.w - mu) * rstd * w.w + bb.w;
        r.x = r.x / (1.f + __expf(-r.x));
        r.y = r.y / (1.f + __expf(-r.y));
        r.z = r.z / (1.f + __expf(-r.z));
        r.w = r.w / (1.f + __expf(-r.w));
        if (r.x != r.x) r.x = 0.f;
        if (r.y != r.y) r.y = 0.f;
        if (r.z != r.z) r.z = 0.f;
        if (r.w != r.w) r.w = 0.f;
        ((float4*)out)[idx] = r;
    }
}

extern "C" void kernel_launch(void* const* d_in, const int* in_sizes, int n_in,
                              void* d_out, int out_size, void* d_ws, size_t ws_size,
                              hipStream_t stream)
{
    const float* x   = (const float*)d_in[0];
    const void*  ei  = d_in[1];
    const float* ea  = (const float*)d_in[2];
    const float* Wl  = (const float*)d_in[3];
    const float* bl  = (const float*)d_in[4];
    const float* W1  = (const float*)d_in[5];
    const float* b1  = (const float*)d_in[6];
    const float* W2  = (const float*)d_in[7];
    const float* b2  = (const float*)d_in[8];
    const float* lnw = (const float*)d_in[9];
    const float* lnb = (const float*)d_in[10];
    float* out = (float*)d_out;

    float* agg = (float*)d_ws;
    float* sc  = agg + AGG_F;       // [0]=s1 [1]=s2 [2]=is64 flag
    int* flag  = (int*)(sc + 2);

    // zero agg + scalars
    (void)hipMemsetAsync(d_ws, 0, (size_t)(AGG_F + 64) * sizeof(float), stream);
    k_detect<<<1, 64, 0, stream>>>((const int*)ei, flag);
    k_edge<<<2048, 256, 0, stream>>>(ea, ei, x, Wl, bl, agg, flag);
    // t (fp32) staged in d_out; k_mlp2 overwrites it row-safely
    k_mlp1<<<(NN + 63) / 64, 256, 0, stream>>>(x, agg, W1, b1, out);
    k_mlp2<<<(NN + 63) / 64, 256, 0, stream>>>(out, x, W2, b2, out, sc);
    k_ln<<<NN * D128 / 4 / 256, 256, 0, stream>>>(out, sc, lnw, lnb);
}

// Round 3
// 558.245 us; speedup vs baseline: 1.0387x; 1.0387x over previous
//
#include <hip/hip_runtime.h>
#include <math.h>

#define NN 50000
#define EE 800000
#define D128 128
#define LN_EPSF 1e-5f

typedef __bf16 bf16_t;
typedef __bf16 bf16x8 __attribute__((ext_vector_type(8)));
typedef float f32x4 __attribute__((ext_vector_type(4)));

// ws float layout: [0 .. NN*D128) agg ; then scalars: [s1, s2, flag(int), ...]
#define AGG_F (NN * D128)

__device__ __forceinline__ bf16x8 cvt8(float4 f0, float4 f1) {
    bf16x8 r;
    r[0] = (bf16_t)f0.x; r[1] = (bf16_t)f0.y; r[2] = (bf16_t)f0.z; r[3] = (bf16_t)f0.w;
    r[4] = (bf16_t)f1.x; r[5] = (bf16_t)f1.y; r[6] = (bf16_t)f1.z; r[7] = (bf16_t)f1.w;
    return r;
}

__device__ __forceinline__ bf16x8 zero8() {
    bf16x8 z;
    #pragma unroll
    for (int j = 0; j < 8; ++j) z[j] = (bf16_t)0.f;
    return z;
}

// Load W (fp32 [k][n]) into LDS as bf16 transposed [n][k], XOR-swizzled so that
// B-fragment ds_read_b128 (8 consecutive k per lane) is ~conflict-free.
__device__ __forceinline__ void load_w_lds(const float* __restrict__ W, bf16_t* Wlds,
                                           const float* __restrict__ bias, float* b_s) {
    int tid = threadIdx.x;
    for (int i = tid; i < D128 * D128; i += 256) {
        int k = i >> 7, n = i & 127;
        Wlds[(n * D128 + k) ^ ((n & 7) << 3)] = (bf16_t)W[i];
    }
    if (tid < D128) b_s[tid] = bias[tid];
    __syncthreads();
}

// detect whether edge_index is int64 (all high dwords of first 64 entries == 0)
__global__ void k_detect(const int* __restrict__ ei32, int* __restrict__ flag) {
    int i = threadIdx.x;
    unsigned long long m = __ballot(ei32[2 * i + 1] == 0);
    if (i == 0) flag[0] = (m == ~0ULL) ? 1 : 0;
}

__device__ __forceinline__ void idx_pair(const void* ei, int is64, int e, int& sj, int& di) {
    if (is64) {
        const long long* p = (const long long*)ei;
        sj = (int)p[e]; di = (int)p[EE + e];
    } else {
        const int* p = (const int*)ei;
        sj = p[e]; di = p[EE + e];
    }
}

// ---- CSR build ----

__global__ __launch_bounds__(256) void k_hist(const void* __restrict__ eidx,
                                              const int* __restrict__ flag,
                                              int* __restrict__ deg) {
    const int is64 = flag[0];
    for (int e = blockIdx.x * 256 + threadIdx.x; e < EE; e += gridDim.x * 256) {
        int sj, di;
        idx_pair(eidx, is64, e, sj, di);
        atomicAdd(&deg[di], 1);
    }
}

// single-block exclusive scan over deg[NN] -> rowptr[NN+1], copy to cursor[NN]
#define SCAN_T 1024
#define SCAN_SPAN 49   // 1024*49 = 50176 >= 50000
__global__ __launch_bounds__(SCAN_T) void k_scan(const int* __restrict__ deg,
                                                 int* __restrict__ rowptr,
                                                 int* __restrict__ cursor) {
    __shared__ int s[SCAN_T];
    const int t = threadIdx.x;
    const int lo = t * SCAN_SPAN;
    const int hi = min(lo + SCAN_SPAN, NN);
    int part = 0;
    for (int i = lo; i < hi; ++i) part += deg[i];
    s[t] = part;
    __syncthreads();
    #pragma unroll
    for (int off = 1; off < SCAN_T; off <<= 1) {
        int v = (t >= off) ? s[t - off] : 0;
        __syncthreads();
        s[t] += v;
        __syncthreads();
    }
    int run = s[t] - part;  // exclusive prefix
    for (int i = lo; i < hi; ++i) {
        rowptr[i] = run;
        cursor[i] = run;
        run += deg[i];
    }
    if (t == SCAN_T - 1) rowptr[NN] = s[SCAN_T - 1];
}

__global__ __launch_bounds__(256) void k_scatter(const void* __restrict__ eidx,
                                                 const int* __restrict__ flag,
                                                 int* __restrict__ cursor,
                                                 int* __restrict__ csr_eid,
                                                 int* __restrict__ csr_src) {
    const int is64 = flag[0];
    for (int e = blockIdx.x * 256 + threadIdx.x; e < EE; e += gridDim.x * 256) {
        int sj, di;
        idx_pair(eidx, is64, e, sj, di);
        int p = atomicAdd(&cursor[di], 1);
        csr_eid[p] = e;
        csr_src[p] = sj;
    }
}

// ---- aggregation: one wave per node, no atomics ----
// agg[n] = sum over incoming edges of relu(x[src] + ea[eid] @ Wl + bl)
__global__ __launch_bounds__(256) void k_agg(
    const float* __restrict__ ea, const float* __restrict__ x,
    const float* __restrict__ Wl, const float* __restrict__ bl,
    const int* __restrict__ csr_eid, const int* __restrict__ csr_src,
    const int* __restrict__ rowptr, float* __restrict__ agg)
{
    __shared__ bf16_t Wlds[D128 * D128];
    __shared__ float bl_s[D128];
    load_w_lds(Wl, Wlds, bl, bl_s);

    const int lane = threadIdx.x & 63, wid = threadIdx.x >> 6;
    const int l15 = lane & 15, lg = lane >> 4;
    const int nwaves = gridDim.x * 4;

    for (int n = blockIdx.x * 4 + wid; n < NN; n += nwaves) {
        const int beg = rowptr[n], end = rowptr[n + 1];
        float sum[8];
        #pragma unroll
        for (int t = 0; t < 8; ++t) sum[t] = 0.f;

        for (int cb = beg; cb < end; cb += 16) {
            const int p = cb + l15;
            const bool v15 = p < end;
            const int eid = v15 ? csr_eid[p] : 0;
            const int src = v15 ? csr_src[p] : 0;

            bf16x8 a[4];
            if (v15) {
                const float* rp = ea + (size_t)eid * D128 + lg * 8;
                #pragma unroll
                for (int s = 0; s < 4; ++s) {
                    float4 f0 = *(const float4*)(rp + s * 32);
                    float4 f1 = *(const float4*)(rp + s * 32 + 4);
                    a[s] = cvt8(f0, f1);
                }
            } else {
                #pragma unroll
                for (int s = 0; s < 4; ++s) a[s] = zero8();
            }

            f32x4 acc[8];
            #pragma unroll
            for (int t = 0; t < 8; ++t) acc[t] = f32x4{0.f, 0.f, 0.f, 0.f};
            #pragma unroll
            for (int s = 0; s < 4; ++s) {
                const int kb = s * 32 + lg * 8;
                #pragma unroll
                for (int t = 0; t < 8; ++t) {
                    const int col = l15 + 16 * t;
                    bf16x8 b = *(const bf16x8*)&Wlds[(col * D128 + kb) ^ ((col & 7) << 3)];
                    acc[t] = __builtin_amdgcn_mfma_f32_16x16x32_bf16(a[s], b, acc[t], 0, 0, 0);
                }
            }

            #pragma unroll
            for (int i = 0; i < 4; ++i) {
                const int r = lg * 4 + i;                  // C row within this 16-edge chunk
                const bool vr = (cb + r) < end;
                const int src_r = __shfl(src, r, 16);      // src held by lane l15==r in group
                const float* xr = x + (size_t)(vr ? src_r : 0) * D128;
                #pragma unroll
                for (int t = 0; t < 8; ++t) {
                    const int c = l15 + 16 * t;
                    float m = fmaxf(acc[t][i] + bl_s[c] + xr[c], 0.f);
                    sum[t] += vr ? m : 0.f;
                }
            }
        }

        // reduce the 4 lg groups (rows) -> per-column totals
        #pragma unroll
        for (int t = 0; t < 8; ++t) {
            sum[t] += __shfl_xor(sum[t], 16);
            sum[t] += __shfl_xor(sum[t], 32);
        }
        if (lg == 0) {
            float* ar = agg + (size_t)n * D128;
            #pragma unroll
            for (int t = 0; t < 8; ++t) ar[l15 + 16 * t] = sum[t];
        }
    }
}

// t = relu((x+agg) @ W1 + b1)  -> stored fp32 into d_out (scratch use)
__global__ __launch_bounds__(256) void k_mlp1(
    const float* __restrict__ x, const float* __restrict__ agg,
    const float* __restrict__ W1, const float* __restrict__ b1,
    float* __restrict__ tbuf)
{
    __shared__ bf16_t Wlds[D128 * D128];
    __shared__ float b_s[D128];
    load_w_lds(W1, Wlds, b1, b_s);

    const int lane = threadIdx.x & 63, wid = threadIdx.x >> 6;
    const int l15 = lane & 15, lg = lane >> 4;
    const int nbase = blockIdx.x * 64 + wid * 16;
    if (nbase >= NN) return;

    const int row = nbase + l15;
    bf16x8 a[4];
    if (row < NN) {
        const float* xr = x + (size_t)row * D128 + lg * 8;
        const float* gr = agg + (size_t)row * D128 + lg * 8;
        #pragma unroll
        for (int s = 0; s < 4; ++s) {
            float4 f0 = *(const float4*)(xr + s * 32);
            float4 f1 = *(const float4*)(xr + s * 32 + 4);
            float4 g0 = *(const float4*)(gr + s * 32);
            float4 g1 = *(const float4*)(gr + s * 32 + 4);
            float4 h0 = {f0.x + g0.x, f0.y + g0.y, f0.z + g0.z, f0.w + g0.w};
            float4 h1 = {f1.x + g1.x, f1.y + g1.y, f1.z + g1.z, f1.w + g1.w};
            a[s] = cvt8(h0, h1);
        }
    } else {
        #pragma unroll
        for (int s = 0; s < 4; ++s) a[s] = zero8();
    }
    f32x4 acc[8];
    #pragma unroll
    for (int t = 0; t < 8; ++t) acc[t] = f32x4{0.f, 0.f, 0.f, 0.f};
    #pragma unroll
    for (int s = 0; s < 4; ++s) {
        const int kb = s * 32 + lg * 8;
        #pragma unroll
        for (int t = 0; t < 8; ++t) {
            const int col = l15 + 16 * t;
            bf16x8 b = *(const bf16x8*)&Wlds[(col * D128 + kb) ^ ((col & 7) << 3)];
            acc[t] = __builtin_amdgcn_mfma_f32_16x16x32_bf16(a[s], b, acc[t], 0, 0, 0);
        }
    }
    #pragma unroll
    for (int i = 0; i < 4; ++i) {
        const int r = nbase + lg * 4 + i;
        if (r < NN) {
            float* tr = tbuf + (size_t)r * D128;
            #pragma unroll
            for (int t = 0; t < 8; ++t) {
                const int c = l15 + 16 * t;
                tr[c] = fmaxf(acc[t][i] + b_s[c], 0.0f);
            }
        }
    }
}

// h2 = t @ W2 + b2 + x  -> d_out (in place over t, row-safe) ; block partial sums -> sc
__global__ __launch_bounds__(256) void k_mlp2(
    const float* __restrict__ tbuf, const float* __restrict__ x,
    const float* __restrict__ W2, const float* __restrict__ b2,
    float* __restrict__ out, float* __restrict__ sc)
{
    __shared__ bf16_t Wlds[D128 * D128];
    __shared__ float b_s[D128];
    __shared__ float red[8];
    load_w_lds(W2, Wlds, b2, b_s);

    const int tid = threadIdx.x;
    const int lane = tid & 63, wid = tid >> 6;
    const int l15 = lane & 15, lg = lane >> 4;
    const int nbase = blockIdx.x * 64 + wid * 16;
    float s1 = 0.f, s2 = 0.f;

    if (nbase < NN) {
        const int row = nbase + l15;
        bf16x8 a[4];
        if (row < NN) {
            const float* rp = tbuf + (size_t)row * D128 + lg * 8;
            #pragma unroll
            for (int s = 0; s < 4; ++s) {
                float4 f0 = *(const float4*)(rp + s * 32);
                float4 f1 = *(const float4*)(rp + s * 32 + 4);
                a[s] = cvt8(f0, f1);
            }
        } else {
            #pragma unroll
            for (int s = 0; s < 4; ++s) a[s] = zero8();
        }
        f32x4 acc[8];
        #pragma unroll
        for (int t = 0; t < 8; ++t) acc[t] = f32x4{0.f, 0.f, 0.f, 0.f};
        #pragma unroll
        for (int s = 0; s < 4; ++s) {
            const int kb = s * 32 + lg * 8;
            #pragma unroll
            for (int t = 0; t < 8; ++t) {
                const int col = l15 + 16 * t;
                bf16x8 b = *(const bf16x8*)&Wlds[(col * D128 + kb) ^ ((col & 7) << 3)];
                acc[t] = __builtin_amdgcn_mfma_f32_16x16x32_bf16(a[s], b, acc[t], 0, 0, 0);
            }
        }
        #pragma unroll
        for (int i = 0; i < 4; ++i) {
            const int r = nbase + lg * 4 + i;
            if (r < NN) {
                #pragma unroll
                for (int t = 0; t < 8; ++t) {
                    const int c = l15 + 16 * t;
                    float v = acc[t][i] + b_s[c] + x[(size_t)r * D128 + c];
                    out[(size_t)r * D128 + c] = v;
                    s1 += v;
                    s2 += v * v;
                }
            }
        }
    }
    // block reduction (all threads participate)
    #pragma unroll
    for (int o = 32; o > 0; o >>= 1) {
        s1 += __shfl_xor(s1, o);
        s2 += __shfl_xor(s2, o);
    }
    if (lane == 0) { red[wid * 2] = s1; red[wid * 2 + 1] = s2; }
    __syncthreads();
    if (tid == 0) {
        float a1 = red[0] + red[2] + red[4] + red[6];
        float a2 = red[1] + red[3] + red[5] + red[7];
        unsafeAtomicAdd(&sc[0], a1);
        unsafeAtomicAdd(&sc[1], a2);
    }
}

// graph-LN + SiLU + nan_to_num, in place on d_out
__global__ __launch_bounds__(256) void k_ln(
    float* __restrict__ out, const float* __restrict__ sc,
    const float* __restrict__ lnw, const float* __restrict__ lnb)
{
    const float inv = 1.0f / (float)(NN * D128);
    const float mu = sc[0] * inv;
    const float var = sc[1] * inv - mu * mu;
    const float rstd = 1.0f / (sqrtf(fmaxf(var, 0.f)) + LN_EPSF);
    const int total = NN * D128 / 4;
    for (int idx = blockIdx.x * 256 + threadIdx.x; idx < total; idx += gridDim.x * 256) {
        float4 h = ((const float4*)out)[idx];
        const int c0 = (idx * 4) & 127;
        float4 w = *(const float4*)(lnw + c0);
        float4 bb = *(const float4*)(lnb + c0);
        float4 r;
        r.x = (h.x - mu) * rstd * w.x + bb.x;
        r.y = (h.y - mu) * rstd * w.y + bb.y;
        r.z = (h.z - mu) * rstd * w.z + bb.z;
        r.w = (h.w - mu) * rstd * w.w + bb.w;
        r.x = r.x / (1.f + __expf(-r.x));
        r.y = r.y / (1.f + __expf(-r.y));
        r.z = r.z / (1.f + __expf(-r.z));
        r.w = r.w / (1.f + __expf(-r.w));
        if (r.x != r.x) r.x = 0.f;
        if (r.y != r.y) r.y = 0.f;
        if (r.z != r.z) r.z = 0.f;
        if (r.w != r.w) r.w = 0.f;
        ((float4*)out)[idx] = r;
    }
}

extern "C" void kernel_launch(void* const* d_in, const int* in_sizes, int n_in,
                              void* d_out, int out_size, void* d_ws, size_t ws_size,
                              hipStream_t stream)
{
    const float* x   = (const float*)d_in[0];
    const void*  ei  = d_in[1];
    const float* ea  = (const float*)d_in[2];
    const float* Wl  = (const float*)d_in[3];
    const float* bl  = (const float*)d_in[4];
    const float* W1  = (const float*)d_in[5];
    const float* b1  = (const float*)d_in[6];
    const float* W2  = (const float*)d_in[7];
    const float* b2  = (const float*)d_in[8];
    const float* lnw = (const float*)d_in[9];
    const float* lnb = (const float*)d_in[10];
    float* out = (float*)d_out;

    float* agg = (float*)d_ws;
    float* sc  = agg + AGG_F;       // [0]=s1 [1]=s2, then flag
    int* flag  = (int*)(sc + 2);

    // CSR scratch lives in d_out (free until k_mlp1 overwrites it)
    int* csr_eid = (int*)d_out;          // [EE]
    int* csr_src = csr_eid + EE;         // [EE]
    int* deg     = csr_src + EE;         // [NN]
    int* rowptr  = deg + NN;             // [NN+1]
    int* cursor  = rowptr + NN + 1;      // [NN]

    (void)hipMemsetAsync(sc, 0, 64 * sizeof(float), stream);
    (void)hipMemsetAsync(deg, 0, NN * sizeof(int), stream);
    k_detect<<<1, 64, 0, stream>>>((const int*)ei, flag);
    k_hist<<<1024, 256, 0, stream>>>(ei, flag, deg);
    k_scan<<<1, SCAN_T, 0, stream>>>(deg, rowptr, cursor);
    k_scatter<<<1024, 256, 0, stream>>>(ei, flag, cursor, csr_eid, csr_src);
    k_agg<<<2048, 256, 0, stream>>>(ea, x, Wl, bl, csr_eid, csr_src, rowptr, agg);
    // t (fp32) staged in d_out (overwrites CSR scratch, which is now consumed)
    k_mlp1<<<(NN + 63) / 64, 256, 0, stream>>>(x, agg, W1, b1, out);
    k_mlp2<<<(NN + 63) / 64, 256, 0, stream>>>(out, x, W2, b2, out, sc);
    k_ln<<<NN * D128 / 4 / 256, 256, 0, stream>>>(out, sc, lnw, lnb);
}

// Round 4
// 454.502 us; speedup vs baseline: 1.2758x; 1.2283x over previous
//
#include <hip/hip_runtime.h>
#include <math.h>

#define NN 50000
#define EE 800000
#define D128 128
#define LN_EPSF 1e-5f

typedef __bf16 bf16_t;
typedef __bf16 bf16x8 __attribute__((ext_vector_type(8)));
typedef float f32x4 __attribute__((ext_vector_type(4)));

// ws float layout: [0 .. NN*D128) agg ; then scalars: [s1, s2, flag(int), ...]
#define AGG_F (NN * D128)

__device__ __forceinline__ bf16x8 cvt8(float4 f0, float4 f1) {
    bf16x8 r;
    r[0] = (bf16_t)f0.x; r[1] = (bf16_t)f0.y; r[2] = (bf16_t)f0.z; r[3] = (bf16_t)f0.w;
    r[4] = (bf16_t)f1.x; r[5] = (bf16_t)f1.y; r[6] = (bf16_t)f1.z; r[7] = (bf16_t)f1.w;
    return r;
}

__device__ __forceinline__ bf16x8 zero8() {
    bf16x8 z;
    #pragma unroll
    for (int j = 0; j < 8; ++j) z[j] = (bf16_t)0.f;
    return z;
}

// Load W (fp32 [k][n]) into LDS as bf16 transposed [n][k], XOR-swizzled so that
// B-fragment ds_read_b128 (8 consecutive k per lane) is ~conflict-free.
__device__ __forceinline__ void load_w_lds(const float* __restrict__ W, bf16_t* Wlds,
                                           const float* __restrict__ bias, float* b_s) {
    int tid = threadIdx.x;
    for (int i = tid; i < D128 * D128; i += 256) {
        int k = i >> 7, n = i & 127;
        Wlds[(n * D128 + k) ^ ((n & 7) << 3)] = (bf16_t)W[i];
    }
    if (tid < D128) b_s[tid] = bias[tid];
    __syncthreads();
}

// detect whether edge_index is int64 (all high dwords of first 64 entries == 0)
__global__ void k_detect(const int* __restrict__ ei32, int* __restrict__ flag) {
    int i = threadIdx.x;
    unsigned long long m = __ballot(ei32[2 * i + 1] == 0);
    if (i == 0) flag[0] = (m == ~0ULL) ? 1 : 0;
}

__device__ __forceinline__ void idx_pair(const void* ei, int is64, int e, int& sj, int& di) {
    if (is64) {
        const long long* p = (const long long*)ei;
        sj = (int)p[e]; di = (int)p[EE + e];
    } else {
        const int* p = (const int*)ei;
        sj = p[e]; di = p[EE + e];
    }
}

// ---- CSR build ----

__global__ __launch_bounds__(256) void k_hist(const void* __restrict__ eidx,
                                              const int* __restrict__ flag,
                                              int* __restrict__ deg) {
    const int is64 = flag[0];
    for (int e = blockIdx.x * 256 + threadIdx.x; e < EE; e += gridDim.x * 256) {
        int sj, di;
        idx_pair(eidx, is64, e, sj, di);
        atomicAdd(&deg[di], 1);
    }
}

// single-block exclusive scan over deg[NN] -> rowptr[NN+1], copy to cursor[NN]
#define SCAN_T 1024
#define SCAN_SPAN 49   // 1024*49 = 50176 >= 50000
__global__ __launch_bounds__(SCAN_T) void k_scan(const int* __restrict__ deg,
                                                 int* __restrict__ rowptr,
                                                 int* __restrict__ cursor) {
    __shared__ int s[SCAN_T];
    const int t = threadIdx.x;
    const int lo = t * SCAN_SPAN;
    const int hi = min(lo + SCAN_SPAN, NN);
    int part = 0;
    for (int i = lo; i < hi; ++i) part += deg[i];
    s[t] = part;
    __syncthreads();
    #pragma unroll
    for (int off = 1; off < SCAN_T; off <<= 1) {
        int v = (t >= off) ? s[t - off] : 0;
        __syncthreads();
        s[t] += v;
        __syncthreads();
    }
    int run = s[t] - part;  // exclusive prefix
    for (int i = lo; i < hi; ++i) {
        rowptr[i] = run;
        cursor[i] = run;
        run += deg[i];
    }
    if (t == SCAN_T - 1) rowptr[NN] = s[SCAN_T - 1];
}

// scatter: one packed int4 {eid, src, dst, 0} per CSR position
__global__ __launch_bounds__(256) void k_scatter(const void* __restrict__ eidx,
                                                 const int* __restrict__ flag,
                                                 int* __restrict__ cursor,
                                                 int4* __restrict__ csr4) {
    const int is64 = flag[0];
    for (int e = blockIdx.x * 256 + threadIdx.x; e < EE; e += gridDim.x * 256) {
        int sj, di;
        idx_pair(eidx, is64, e, sj, di);
        int p = atomicAdd(&cursor[di], 1);
        csr4[p] = make_int4(e, sj, di, 0);
    }
}

// ---- aggregation: flat 16-edge tiles, in-wave segmented reduction ----
// agg[n] = sum over incoming edges of relu(x[src] + ea[eid] @ Wl + bl)
// agg must be pre-zeroed (boundary runs use atomicAdd; deg-0 nodes untouched).
__global__ __launch_bounds__(256) void k_agg2(
    const float* __restrict__ ea, const float* __restrict__ x,
    const float* __restrict__ Wl, const float* __restrict__ bl,
    const int4* __restrict__ csr4, float* __restrict__ agg)
{
    __shared__ bf16_t Wlds[D128 * D128];
    __shared__ float bl_s[D128];
    __shared__ float msgs[4][16 * 68];   // per-wave 16 rows x 64 cols (pad 68)
    load_w_lds(Wl, Wlds, bl, bl_s);

    const int lane = threadIdx.x & 63, wid = threadIdx.x >> 6;
    const int l15 = lane & 15, lg = lane >> 4;
    float* msg = msgs[wid];
    const int nwaves = gridDim.x * 4;
    const int NT = EE / 16;   // 50000 exact

    for (int tile = blockIdx.x * 4 + wid; tile < NT; tile += nwaves) {
        const int p0 = tile * 16;
        const int4 me = csr4[p0 + l15];
        const int eid = me.x, src_l = me.y, dst_l = me.z;
        const int dstm1 = (p0 > 0) ? csr4[p0 - 1].z : -1;
        const int dstp16 = (p0 + 16 < EE) ? csr4[p0 + 16].z : -2;

        // A fragments: 16 edges x K=128
        bf16x8 a[4];
        {
            const float* rp = ea + (size_t)eid * D128 + lg * 8;
            #pragma unroll
            for (int s = 0; s < 4; ++s) {
                float4 f0 = *(const float4*)(rp + s * 32);
                float4 f1 = *(const float4*)(rp + s * 32 + 4);
                a[s] = cvt8(f0, f1);
            }
        }
        f32x4 acc[8];
        #pragma unroll
        for (int t = 0; t < 8; ++t) acc[t] = f32x4{0.f, 0.f, 0.f, 0.f};
        #pragma unroll
        for (int s = 0; s < 4; ++s) {
            const int kb = s * 32 + lg * 8;
            #pragma unroll
            for (int t = 0; t < 8; ++t) {
                const int col = l15 + 16 * t;
                bf16x8 b = *(const bf16x8*)&Wlds[(col * D128 + kb) ^ ((col & 7) << 3)];
                acc[t] = __builtin_amdgcn_mfma_f32_16x16x32_bf16(a[s], b, acc[t], 0, 0, 0);
            }
        }

        // run-head mask over the 16 rows (dst-sorted)
        const int prev = __shfl_up(dst_l, 1, 16);
        const bool head = (l15 == 0) || (dst_l != prev);
        const unsigned mask16 = (unsigned)(__ballot(head) & 0xffffu);

        #pragma unroll
        for (int hf = 0; hf < 2; ++hf) {
            // msg rows -> LDS (relu(acc + bl + x[src]) fused)
            #pragma unroll
            for (int i = 0; i < 4; ++i) {
                const int r = lg * 4 + i;
                const int src_r = __shfl(src_l, r, 16);
                const float* xr = x + (size_t)src_r * D128 + hf * 64;
                #pragma unroll
                for (int t = 0; t < 4; ++t) {
                    const int cl = l15 + 16 * t;   // col within this 64-col half
                    float v = fmaxf(acc[hf * 4 + t][i] + bl_s[hf * 64 + cl] + xr[cl], 0.f);
                    msg[r * 68 + cl] = v;
                }
            }
            asm volatile("s_waitcnt lgkmcnt(0)" ::: "memory");
            // segmented reduce: one run at a time, lane = col
            unsigned m = mask16;
            while (m) {
                const int h = __builtin_ctz(m);
                m &= m - 1;
                const int nxt = m ? __builtin_ctz(m) : 16;
                const int dst_run = __shfl(dst_l, h, 16);
                float s = 0.f;
                for (int r = h; r < nxt; ++r) s += msg[r * 68 + lane];
                const bool part = (h == 0 && dst_run == dstm1) ||
                                  (nxt == 16 && dst_run == dstp16);
                float* ap = agg + (size_t)dst_run * D128 + hf * 64 + lane;
                if (part) unsafeAtomicAdd(ap, s);
                else *ap = s;
            }
            asm volatile("s_waitcnt lgkmcnt(0)" ::: "memory");
        }
    }
}

// t = relu((x+agg) @ W1 + b1)  -> stored fp32 into d_out (scratch use)
__global__ __launch_bounds__(256) void k_mlp1(
    const float* __restrict__ x, const float* __restrict__ agg,
    const float* __restrict__ W1, const float* __restrict__ b1,
    float* __restrict__ tbuf)
{
    __shared__ bf16_t Wlds[D128 * D128];
    __shared__ float b_s[D128];
    load_w_lds(W1, Wlds, b1, b_s);

    const int lane = threadIdx.x & 63, wid = threadIdx.x >> 6;
    const int l15 = lane & 15, lg = lane >> 4;
    const int nbase = blockIdx.x * 64 + wid * 16;
    if (nbase >= NN) return;

    const int row = nbase + l15;
    bf16x8 a[4];
    if (row < NN) {
        const float* xr = x + (size_t)row * D128 + lg * 8;
        const float* gr = agg + (size_t)row * D128 + lg * 8;
        #pragma unroll
        for (int s = 0; s < 4; ++s) {
            float4 f0 = *(const float4*)(xr + s * 32);
            float4 f1 = *(const float4*)(xr + s * 32 + 4);
            float4 g0 = *(const float4*)(gr + s * 32);
            float4 g1 = *(const float4*)(gr + s * 32 + 4);
            float4 h0 = {f0.x + g0.x, f0.y + g0.y, f0.z + g0.z, f0.w + g0.w};
            float4 h1 = {f1.x + g1.x, f1.y + g1.y, f1.z + g1.z, f1.w + g1.w};
            a[s] = cvt8(h0, h1);
        }
    } else {
        #pragma unroll
        for (int s = 0; s < 4; ++s) a[s] = zero8();
    }
    f32x4 acc[8];
    #pragma unroll
    for (int t = 0; t < 8; ++t) acc[t] = f32x4{0.f, 0.f, 0.f, 0.f};
    #pragma unroll
    for (int s = 0; s < 4; ++s) {
        const int kb = s * 32 + lg * 8;
        #pragma unroll
        for (int t = 0; t < 8; ++t) {
            const int col = l15 + 16 * t;
            bf16x8 b = *(const bf16x8*)&Wlds[(col * D128 + kb) ^ ((col & 7) << 3)];
            acc[t] = __builtin_amdgcn_mfma_f32_16x16x32_bf16(a[s], b, acc[t], 0, 0, 0);
        }
    }
    #pragma unroll
    for (int i = 0; i < 4; ++i) {
        const int r = nbase + lg * 4 + i;
        if (r < NN) {
            float* tr = tbuf + (size_t)r * D128;
            #pragma unroll
            for (int t = 0; t < 8; ++t) {
                const int c = l15 + 16 * t;
                tr[c] = fmaxf(acc[t][i] + b_s[c], 0.0f);
            }
        }
    }
}

// h2 = t @ W2 + b2 + x  -> d_out (in place over t, row-safe) ; block partial sums -> sc
__global__ __launch_bounds__(256) void k_mlp2(
    const float* __restrict__ tbuf, const float* __restrict__ x,
    const float* __restrict__ W2, const float* __restrict__ b2,
    float* __restrict__ out, float* __restrict__ sc)
{
    __shared__ bf16_t Wlds[D128 * D128];
    __shared__ float b_s[D128];
    __shared__ float red[8];
    load_w_lds(W2, Wlds, b2, b_s);

    const int tid = threadIdx.x;
    const int lane = tid & 63, wid = tid >> 6;
    const int l15 = lane & 15, lg = lane >> 4;
    const int nbase = blockIdx.x * 64 + wid * 16;
    float s1 = 0.f, s2 = 0.f;

    if (nbase < NN) {
        const int row = nbase + l15;
        bf16x8 a[4];
        if (row < NN) {
            const float* rp = tbuf + (size_t)row * D128 + lg * 8;
            #pragma unroll
            for (int s = 0; s < 4; ++s) {
                float4 f0 = *(const float4*)(rp + s * 32);
                float4 f1 = *(const float4*)(rp + s * 32 + 4);
                a[s] = cvt8(f0, f1);
            }
        } else {
            #pragma unroll
            for (int s = 0; s < 4; ++s) a[s] = zero8();
        }
        f32x4 acc[8];
        #pragma unroll
        for (int t = 0; t < 8; ++t) acc[t] = f32x4{0.f, 0.f, 0.f, 0.f};
        #pragma unroll
        for (int s = 0; s < 4; ++s) {
            const int kb = s * 32 + lg * 8;
            #pragma unroll
            for (int t = 0; t < 8; ++t) {
                const int col = l15 + 16 * t;
                bf16x8 b = *(const bf16x8*)&Wlds[(col * D128 + kb) ^ ((col & 7) << 3)];
                acc[t] = __builtin_amdgcn_mfma_f32_16x16x32_bf16(a[s], b, acc[t], 0, 0, 0);
            }
        }
        #pragma unroll
        for (int i = 0; i < 4; ++i) {
            const int r = nbase + lg * 4 + i;
            if (r < NN) {
                #pragma unroll
                for (int t = 0; t < 8; ++t) {
                    const int c = l15 + 16 * t;
                    float v = acc[t][i] + b_s[c] + x[(size_t)r * D128 + c];
                    out[(size_t)r * D128 + c] = v;
                    s1 += v;
                    s2 += v * v;
                }
            }
        }
    }
    // block reduction (all threads participate)
    #pragma unroll
    for (int o = 32; o > 0; o >>= 1) {
        s1 += __shfl_xor(s1, o);
        s2 += __shfl_xor(s2, o);
    }
    if (lane == 0) { red[wid * 2] = s1; red[wid * 2 + 1] = s2; }
    __syncthreads();
    if (tid == 0) {
        float a1 = red[0] + red[2] + red[4] + red[6];
        float a2 = red[1] + red[3] + red[5] + red[7];
        unsafeAtomicAdd(&sc[0], a1);
        unsafeAtomicAdd(&sc[1], a2);
    }
}

// graph-LN + SiLU + nan_to_num, in place on d_out
__global__ __launch_bounds__(256) void k_ln(
    float* __restrict__ out, const float* __restrict__ sc,
    const float* __restrict__ lnw, const float* __restrict__ lnb)
{
    const float inv = 1.0f / (float)(NN * D128);
    const float mu = sc[0] * inv;
    const float var = sc[1] * inv - mu * mu;
    const float rstd = 1.0f / (sqrtf(fmaxf(var, 0.f)) + LN_EPSF);
    const int total = NN * D128 / 4;
    for (int idx = blockIdx.x * 256 + threadIdx.x; idx < total; idx += gridDim.x * 256) {
        float4 h = ((const float4*)out)[idx];
        const int c0 = (idx * 4) & 127;
        float4 w = *(const float4*)(lnw + c0);
        float4 bb = *(const float4*)(lnb + c0);
        float4 r;
        r.x = (h.x - mu) * rstd * w.x + bb.x;
        r.y = (h.y - mu) * rstd * w.y + bb.y;
        r.z = (h.z - mu) * rstd * w.z + bb.z;
        r.w = (h.w - mu) * rstd * w.w + bb.w;
        r.x = r.x / (1.f + __expf(-r.x));
        r.y = r.y / (1.f + __expf(-r.y));
        r.z = r.z / (1.f + __expf(-r.z));
        r.w = r.w / (1.f + __expf(-r.w));
        if (r.x != r.x) r.x = 0.f;
        if (r.y != r.y) r.y = 0.f;
        if (r.z != r.z) r.z = 0.f;
        if (r.w != r.w) r.w = 0.f;
        ((float4*)out)[idx] = r;
    }
}

extern "C" void kernel_launch(void* const* d_in, const int* in_sizes, int n_in,
                              void* d_out, int out_size, void* d_ws, size_t ws_size,
                              hipStream_t stream)
{
    const float* x   = (const float*)d_in[0];
    const void*  ei  = d_in[1];
    const float* ea  = (const float*)d_in[2];
    const float* Wl  = (const float*)d_in[3];
    const float* bl  = (const float*)d_in[4];
    const float* W1  = (const float*)d_in[5];
    const float* b1  = (const float*)d_in[6];
    const float* W2  = (const float*)d_in[7];
    const float* b2  = (const float*)d_in[8];
    const float* lnw = (const float*)d_in[9];
    const float* lnb = (const float*)d_in[10];
    float* out = (float*)d_out;

    float* agg = (float*)d_ws;
    float* sc  = agg + AGG_F;       // [0]=s1 [1]=s2, then flag
    int* flag  = (int*)(sc + 2);

    // CSR scratch lives in d_out (free until k_mlp1 overwrites it)
    int4* csr4  = (int4*)d_out;          // [EE] packed {eid, src, dst, 0}
    int* deg    = (int*)(csr4 + EE);     // [NN]
    int* rowptr = deg + NN;              // [NN+1]
    int* cursor = rowptr + NN + 1;       // [NN]

    // zero agg + scalars + deg
    (void)hipMemsetAsync(d_ws, 0, (size_t)(AGG_F + 64) * sizeof(float), stream);
    (void)hipMemsetAsync(deg, 0, NN * sizeof(int), stream);
    k_detect<<<1, 64, 0, stream>>>((const int*)ei, flag);
    k_hist<<<1024, 256, 0, stream>>>(ei, flag, deg);
    k_scan<<<1, SCAN_T, 0, stream>>>(deg, rowptr, cursor);
    k_scatter<<<1024, 256, 0, stream>>>(ei, flag, cursor, csr4);
    k_agg2<<<1024, 256, 0, stream>>>(ea, x, Wl, bl, csr4, agg);
    // t (fp32) staged in d_out (overwrites CSR scratch, which is now consumed)
    k_mlp1<<<(NN + 63) / 64, 256, 0, stream>>>(x, agg, W1, b1, out);
    k_mlp2<<<(NN + 63) / 64, 256, 0, stream>>>(out, x, W2, b2, out, sc);
    k_ln<<<NN * D128 / 4 / 256, 256, 0, stream>>>(out, sc, lnw, lnb);
}

// Round 5
// 415.322 us; speedup vs baseline: 1.3962x; 1.0943x over previous
//
#include <hip/hip_runtime.h>
#include <math.h>

#define NN 50000
#define EE 800000
#define D128 128
#define LN_EPSF 1e-5f

typedef __bf16 bf16_t;
typedef __bf16 bf16x8 __attribute__((ext_vector_type(8)));
typedef float f32x4 __attribute__((ext_vector_type(4)));

// ws float layout: [0 .. NN*D128) agg ; then scalars: [s1, s2, flag(int), ...]
#define AGG_F (NN * D128)

__device__ __forceinline__ bf16x8 cvt8(float4 f0, float4 f1) {
    bf16x8 r;
    r[0] = (bf16_t)f0.x; r[1] = (bf16_t)f0.y; r[2] = (bf16_t)f0.z; r[3] = (bf16_t)f0.w;
    r[4] = (bf16_t)f1.x; r[5] = (bf16_t)f1.y; r[6] = (bf16_t)f1.z; r[7] = (bf16_t)f1.w;
    return r;
}

__device__ __forceinline__ bf16x8 zero8() {
    bf16x8 z;
    #pragma unroll
    for (int j = 0; j < 8; ++j) z[j] = (bf16_t)0.f;
    return z;
}

// Load W (fp32 [k][n]) into LDS as bf16 transposed [n][k], XOR-swizzled so that
// B-fragment ds_read_b128 (8 consecutive k per lane) is ~conflict-free.
__device__ __forceinline__ void load_w_lds(const float* __restrict__ W, bf16_t* Wlds,
                                           const float* __restrict__ bias, float* b_s) {
    int tid = threadIdx.x;
    for (int i = tid; i < D128 * D128; i += 256) {
        int k = i >> 7, n = i & 127;
        Wlds[(n * D128 + k) ^ ((n & 7) << 3)] = (bf16_t)W[i];
    }
    if (tid < D128) b_s[tid] = bias[tid];
    __syncthreads();
}

// zero agg (float4), deg, and scalar accumulators — replaces the pathologically
// slow graph-captured rocclr fillBuffer (240us) with a ~6us streaming kernel.
__global__ __launch_bounds__(256) void k_zero(float4* __restrict__ agg4,
                                              int* __restrict__ deg,
                                              float* __restrict__ sc) {
    const int idx = blockIdx.x * 256 + threadIdx.x;
    const int stride = gridDim.x * 256;
    const float4 z = {0.f, 0.f, 0.f, 0.f};
    for (int i = idx; i < AGG_F / 4; i += stride) agg4[i] = z;
    for (int i = idx; i < NN; i += stride) deg[i] = 0;
    if (idx == 0) { sc[0] = 0.f; sc[1] = 0.f; }
}

// detect whether edge_index is int64 (all high dwords of first 64 entries == 0)
__global__ void k_detect(const int* __restrict__ ei32, int* __restrict__ flag) {
    int i = threadIdx.x;
    unsigned long long m = __ballot(ei32[2 * i + 1] == 0);
    if (i == 0) flag[0] = (m == ~0ULL) ? 1 : 0;
}

__device__ __forceinline__ void idx_pair(const void* ei, int is64, int e, int& sj, int& di) {
    if (is64) {
        const long long* p = (const long long*)ei;
        sj = (int)p[e]; di = (int)p[EE + e];
    } else {
        const int* p = (const int*)ei;
        sj = p[e]; di = p[EE + e];
    }
}

// ---- CSR build ----

__global__ __launch_bounds__(256) void k_hist(const void* __restrict__ eidx,
                                              const int* __restrict__ flag,
                                              int* __restrict__ deg) {
    const int is64 = flag[0];
    for (int e = blockIdx.x * 256 + threadIdx.x; e < EE; e += gridDim.x * 256) {
        int sj, di;
        idx_pair(eidx, is64, e, sj, di);
        atomicAdd(&deg[di], 1);
    }
}

// single-block exclusive scan over deg[NN] -> rowptr[NN+1], copy to cursor[NN]
#define SCAN_T 1024
#define SCAN_SPAN 49   // 1024*49 = 50176 >= 50000
__global__ __launch_bounds__(SCAN_T) void k_scan(const int* __restrict__ deg,
                                                 int* __restrict__ rowptr,
                                                 int* __restrict__ cursor) {
    __shared__ int s[SCAN_T];
    const int t = threadIdx.x;
    const int lo = t * SCAN_SPAN;
    const int hi = min(lo + SCAN_SPAN, NN);
    int part = 0;
    for (int i = lo; i < hi; ++i) part += deg[i];
    s[t] = part;
    __syncthreads();
    #pragma unroll
    for (int off = 1; off < SCAN_T; off <<= 1) {
        int v = (t >= off) ? s[t - off] : 0;
        __syncthreads();
        s[t] += v;
        __syncthreads();
    }
    int run = s[t] - part;  // exclusive prefix
    for (int i = lo; i < hi; ++i) {
        rowptr[i] = run;
        cursor[i] = run;
        run += deg[i];
    }
    if (t == SCAN_T - 1) rowptr[NN] = s[SCAN_T - 1];
}

// scatter: one packed int4 {eid, src, dst, 0} per CSR position
__global__ __launch_bounds__(256) void k_scatter(const void* __restrict__ eidx,
                                                 const int* __restrict__ flag,
                                                 int* __restrict__ cursor,
                                                 int4* __restrict__ csr4) {
    const int is64 = flag[0];
    for (int e = blockIdx.x * 256 + threadIdx.x; e < EE; e += gridDim.x * 256) {
        int sj, di;
        idx_pair(eidx, is64, e, sj, di);
        int p = atomicAdd(&cursor[di], 1);
        csr4[p] = make_int4(e, sj, di, 0);
    }
}

// ---- aggregation: flat 16-edge tiles, in-wave segmented reduction ----
// agg[n] = sum over incoming edges of relu(x[src] + ea[eid] @ Wl + bl)
// agg must be pre-zeroed (boundary runs use atomicAdd; deg-0 nodes untouched).
__global__ __launch_bounds__(256) void k_agg2(
    const float* __restrict__ ea, const float* __restrict__ x,
    const float* __restrict__ Wl, const float* __restrict__ bl,
    const int4* __restrict__ csr4, float* __restrict__ agg)
{
    __shared__ bf16_t Wlds[D128 * D128];
    __shared__ float bl_s[D128];
    __shared__ float msgs[4][16 * 68];   // per-wave 16 rows x 64 cols (pad 68)
    load_w_lds(Wl, Wlds, bl, bl_s);

    const int lane = threadIdx.x & 63, wid = threadIdx.x >> 6;
    const int l15 = lane & 15, lg = lane >> 4;
    float* msg = msgs[wid];
    const int nwaves = gridDim.x * 4;
    const int NT = EE / 16;   // 50000 exact

    for (int tile = blockIdx.x * 4 + wid; tile < NT; tile += nwaves) {
        const int p0 = tile * 16;
        const int4 me = csr4[p0 + l15];
        const int eid = me.x, src_l = me.y, dst_l = me.z;
        const int dstm1 = (p0 > 0) ? csr4[p0 - 1].z : -1;
        const int dstp16 = (p0 + 16 < EE) ? csr4[p0 + 16].z : -2;

        // A fragments: 16 edges x K=128
        bf16x8 a[4];
        {
            const float* rp = ea + (size_t)eid * D128 + lg * 8;
            #pragma unroll
            for (int s = 0; s < 4; ++s) {
                float4 f0 = *(const float4*)(rp + s * 32);
                float4 f1 = *(const float4*)(rp + s * 32 + 4);
                a[s] = cvt8(f0, f1);
            }
        }
        f32x4 acc[8];
        #pragma unroll
        for (int t = 0; t < 8; ++t) acc[t] = f32x4{0.f, 0.f, 0.f, 0.f};
        #pragma unroll
        for (int s = 0; s < 4; ++s) {
            const int kb = s * 32 + lg * 8;
            #pragma unroll
            for (int t = 0; t < 8; ++t) {
                const int col = l15 + 16 * t;
                bf16x8 b = *(const bf16x8*)&Wlds[(col * D128 + kb) ^ ((col & 7) << 3)];
                acc[t] = __builtin_amdgcn_mfma_f32_16x16x32_bf16(a[s], b, acc[t], 0, 0, 0);
            }
        }

        // run-head mask over the 16 rows (dst-sorted)
        const int prev = __shfl_up(dst_l, 1, 16);
        const bool head = (l15 == 0) || (dst_l != prev);
        const unsigned mask16 = (unsigned)(__ballot(head) & 0xffffu);

        #pragma unroll
        for (int hf = 0; hf < 2; ++hf) {
            // msg rows -> LDS (relu(acc + bl + x[src]) fused)
            #pragma unroll
            for (int i = 0; i < 4; ++i) {
                const int r = lg * 4 + i;
                const int src_r = __shfl(src_l, r, 16);
                const float* xr = x + (size_t)src_r * D128 + hf * 64;
                #pragma unroll
                for (int t = 0; t < 4; ++t) {
                    const int cl = l15 + 16 * t;   // col within this 64-col half
                    float v = fmaxf(acc[hf * 4 + t][i] + bl_s[hf * 64 + cl] + xr[cl], 0.f);
                    msg[r * 68 + cl] = v;
                }
            }
            asm volatile("s_waitcnt lgkmcnt(0)" ::: "memory");
            // segmented reduce: one run at a time, lane = col
            unsigned m = mask16;
            while (m) {
                const int h = __builtin_ctz(m);
                m &= m - 1;
                const int nxt = m ? __builtin_ctz(m) : 16;
                const int dst_run = __shfl(dst_l, h, 16);
                float s = 0.f;
                for (int r = h; r < nxt; ++r) s += msg[r * 68 + lane];
                const bool part = (h == 0 && dst_run == dstm1) ||
                                  (nxt == 16 && dst_run == dstp16);
                float* ap = agg + (size_t)dst_run * D128 + hf * 64 + lane;
                if (part) unsafeAtomicAdd(ap, s);
                else *ap = s;
            }
            asm volatile("s_waitcnt lgkmcnt(0)" ::: "memory");
        }
    }
}

// t = relu((x+agg) @ W1 + b1)  -> stored fp32 into d_out (scratch use)
__global__ __launch_bounds__(256) void k_mlp1(
    const float* __restrict__ x, const float* __restrict__ agg,
    const float* __restrict__ W1, const float* __restrict__ b1,
    float* __restrict__ tbuf)
{
    __shared__ bf16_t Wlds[D128 * D128];
    __shared__ float b_s[D128];
    load_w_lds(W1, Wlds, b1, b_s);

    const int lane = threadIdx.x & 63, wid = threadIdx.x >> 6;
    const int l15 = lane & 15, lg = lane >> 4;
    const int nbase = blockIdx.x * 64 + wid * 16;
    if (nbase >= NN) return;

    const int row = nbase + l15;
    bf16x8 a[4];
    if (row < NN) {
        const float* xr = x + (size_t)row * D128 + lg * 8;
        const float* gr = agg + (size_t)row * D128 + lg * 8;
        #pragma unroll
        for (int s = 0; s < 4; ++s) {
            float4 f0 = *(const float4*)(xr + s * 32);
            float4 f1 = *(const float4*)(xr + s * 32 + 4);
            float4 g0 = *(const float4*)(gr + s * 32);
            float4 g1 = *(const float4*)(gr + s * 32 + 4);
            float4 h0 = {f0.x + g0.x, f0.y + g0.y, f0.z + g0.z, f0.w + g0.w};
            float4 h1 = {f1.x + g1.x, f1.y + g1.y, f1.z + g1.z, f1.w + g1.w};
            a[s] = cvt8(h0, h1);
        }
    } else {
        #pragma unroll
        for (int s = 0; s < 4; ++s) a[s] = zero8();
    }
    f32x4 acc[8];
    #pragma unroll
    for (int t = 0; t < 8; ++t) acc[t] = f32x4{0.f, 0.f, 0.f, 0.f};
    #pragma unroll
    for (int s = 0; s < 4; ++s) {
        const int kb = s * 32 + lg * 8;
        #pragma unroll
        for (int t = 0; t < 8; ++t) {
            const int col = l15 + 16 * t;
            bf16x8 b = *(const bf16x8*)&Wlds[(col * D128 + kb) ^ ((col & 7) << 3)];
            acc[t] = __builtin_amdgcn_mfma_f32_16x16x32_bf16(a[s], b, acc[t], 0, 0, 0);
        }
    }
    #pragma unroll
    for (int i = 0; i < 4; ++i) {
        const int r = nbase + lg * 4 + i;
        if (r < NN) {
            float* tr = tbuf + (size_t)r * D128;
            #pragma unroll
            for (int t = 0; t < 8; ++t) {
                const int c = l15 + 16 * t;
                tr[c] = fmaxf(acc[t][i] + b_s[c], 0.0f);
            }
        }
    }
}

// h2 = t @ W2 + b2 + x  -> d_out (in place over t, row-safe) ; block partial sums -> sc
__global__ __launch_bounds__(256) void k_mlp2(
    const float* __restrict__ tbuf, const float* __restrict__ x,
    const float* __restrict__ W2, const float* __restrict__ b2,
    float* __restrict__ out, float* __restrict__ sc)
{
    __shared__ bf16_t Wlds[D128 * D128];
    __shared__ float b_s[D128];
    __shared__ float red[8];
    load_w_lds(W2, Wlds, b2, b_s);

    const int tid = threadIdx.x;
    const int lane = tid & 63, wid = tid >> 6;
    const int l15 = lane & 15, lg = lane >> 4;
    const int nbase = blockIdx.x * 64 + wid * 16;
    float s1 = 0.f, s2 = 0.f;

    if (nbase < NN) {
        const int row = nbase + l15;
        bf16x8 a[4];
        if (row < NN) {
            const float* rp = tbuf + (size_t)row * D128 + lg * 8;
            #pragma unroll
            for (int s = 0; s < 4; ++s) {
                float4 f0 = *(const float4*)(rp + s * 32);
                float4 f1 = *(const float4*)(rp + s * 32 + 4);
                a[s] = cvt8(f0, f1);
            }
        } else {
            #pragma unroll
            for (int s = 0; s < 4; ++s) a[s] = zero8();
        }
        f32x4 acc[8];
        #pragma unroll
        for (int t = 0; t < 8; ++t) acc[t] = f32x4{0.f, 0.f, 0.f, 0.f};
        #pragma unroll
        for (int s = 0; s < 4; ++s) {
            const int kb = s * 32 + lg * 8;
            #pragma unroll
            for (int t = 0; t < 8; ++t) {
                const int col = l15 + 16 * t;
                bf16x8 b = *(const bf16x8*)&Wlds[(col * D128 + kb) ^ ((col & 7) << 3)];
                acc[t] = __builtin_amdgcn_mfma_f32_16x16x32_bf16(a[s], b, acc[t], 0, 0, 0);
            }
        }
        #pragma unroll
        for (int i = 0; i < 4; ++i) {
            const int r = nbase + lg * 4 + i;
            if (r < NN) {
                #pragma unroll
                for (int t = 0; t < 8; ++t) {
                    const int c = l15 + 16 * t;
                    float v = acc[t][i] + b_s[c] + x[(size_t)r * D128 + c];
                    out[(size_t)r * D128 + c] = v;
                    s1 += v;
                    s2 += v * v;
                }
            }
        }
    }
    // block reduction (all threads participate)
    #pragma unroll
    for (int o = 32; o > 0; o >>= 1) {
        s1 += __shfl_xor(s1, o);
        s2 += __shfl_xor(s2, o);
    }
    if (lane == 0) { red[wid * 2] = s1; red[wid * 2 + 1] = s2; }
    __syncthreads();
    if (tid == 0) {
        float a1 = red[0] + red[2] + red[4] + red[6];
        float a2 = red[1] + red[3] + red[5] + red[7];
        unsafeAtomicAdd(&sc[0], a1);
        unsafeAtomicAdd(&sc[1], a2);
    }
}

// graph-LN + SiLU + nan_to_num, in place on d_out
__global__ __launch_bounds__(256) void k_ln(
    float* __restrict__ out, const float* __restrict__ sc,
    const float* __restrict__ lnw, const float* __restrict__ lnb)
{
    const float inv = 1.0f / (float)(NN * D128);
    const float mu = sc[0] * inv;
    const float var = sc[1] * inv - mu * mu;
    const float rstd = 1.0f / (sqrtf(fmaxf(var, 0.f)) + LN_EPSF);
    const int total = NN * D128 / 4;
    for (int idx = blockIdx.x * 256 + threadIdx.x; idx < total; idx += gridDim.x * 256) {
        float4 h = ((const float4*)out)[idx];
        const int c0 = (idx * 4) & 127;
        float4 w = *(const float4*)(lnw + c0);
        float4 bb = *(const float4*)(lnb + c0);
        float4 r;
        r.x = (h.x - mu) * rstd * w.x + bb.x;
        r.y = (h.y - mu) * rstd * w.y + bb.y;
        r.z = (h.z - mu) * rstd * w.z + bb.z;
        r.w = (h.w - mu) * rstd * w.w + bb.w;
        r.x = r.x / (1.f + __expf(-r.x));
        r.y = r.y / (1.f + __expf(-r.y));
        r.z = r.z / (1.f + __expf(-r.z));
        r.w = r.w / (1.f + __expf(-r.w));
        if (r.x != r.x) r.x = 0.f;
        if (r.y != r.y) r.y = 0.f;
        if (r.z != r.z) r.z = 0.f;
        if (r.w != r.w) r.w = 0.f;
        ((float4*)out)[idx] = r;
    }
}

extern "C" void kernel_launch(void* const* d_in, const int* in_sizes, int n_in,
                              void* d_out, int out_size, void* d_ws, size_t ws_size,
                              hipStream_t stream)
{
    const float* x   = (const float*)d_in[0];
    const void*  ei  = d_in[1];
    const float* ea  = (const float*)d_in[2];
    const float* Wl  = (const float*)d_in[3];
    const float* bl  = (const float*)d_in[4];
    const float* W1  = (const float*)d_in[5];
    const float* b1  = (const float*)d_in[6];
    const float* W2  = (const float*)d_in[7];
    const float* b2  = (const float*)d_in[8];
    const float* lnw = (const float*)d_in[9];
    const float* lnb = (const float*)d_in[10];
    float* out = (float*)d_out;

    float* agg = (float*)d_ws;
    float* sc  = agg + AGG_F;       // [0]=s1 [1]=s2, then flag
    int* flag  = (int*)(sc + 2);

    // CSR scratch lives in d_out (free until k_mlp1 overwrites it)
    int4* csr4  = (int4*)d_out;          // [EE] packed {eid, src, dst, 0}
    int* deg    = (int*)(csr4 + EE);     // [NN]
    int* rowptr = deg + NN;              // [NN+1]
    int* cursor = rowptr + NN + 1;       // [NN]

    k_zero<<<2048, 256, 0, stream>>>((float4*)agg, deg, sc);
    k_detect<<<1, 64, 0, stream>>>((const int*)ei, flag);
    k_hist<<<1024, 256, 0, stream>>>(ei, flag, deg);
    k_scan<<<1, SCAN_T, 0, stream>>>(deg, rowptr, cursor);
    k_scatter<<<1024, 256, 0, stream>>>(ei, flag, cursor, csr4);
    k_agg2<<<768, 256, 0, stream>>>(ea, x, Wl, bl, csr4, agg);
    // t (fp32) staged in d_out (overwrites CSR scratch, which is now consumed)
    k_mlp1<<<(NN + 63) / 64, 256, 0, stream>>>(x, agg, W1, b1, out);
    k_mlp2<<<(NN + 63) / 64, 256, 0, stream>>>(out, x, W2, b2, out, sc);
    k_ln<<<NN * D128 / 4 / 256, 256, 0, stream>>>(out, sc, lnw, lnb);
}